// Round 12
// baseline (64.973 us; speedup 1.0000x reference)
//
#include <hip/hip_runtime.h>

// upfirdn2d specialized: up=2, down=1, pad0=2, eff trailing pad 2,
// 4x4 kernel, input (1024, 128, 128) f32 -> output (1024, 256, 256) f32.
//
// R12 = R11 with PLAIN stores instead of nontemporal (A/B test: our NT
// write stream runs 4.9 TB/s vs fillBuffer's 7.0 TB/s plain-store rate;
// checking whether the NT no-allocate path throttles the L2 drain).
// Everything else identical: one thread = input row-pair (r0,r0+1) ->
// 4 output rows; every store wave-dense (64 lanes x 16B = 1KB row).

typedef float f4 __attribute__((ext_vector_type(4)));
typedef f4 __attribute__((aligned(4))) f4u;  // 4B-aligned vector load

// Remap clamped load v to A0..A3 = in[2t-1 .. 2t+2] (zero-pad at edges).
#define REMAP(v, A)                                                       \
  const float A##0 = L ? 0.f : (R ? v.y : v.x);                           \
  const float A##1 = L ? v.x : (R ? v.z : v.y);                           \
  const float A##2 = L ? v.y : (R ? v.w : v.z);                           \
  const float A##3 = L ? v.z : (R ? 0.f : v.w);

// One output row (cols 4t..4t+3) from remapped rows A (upper) and B
// (lower): even cols use (u0,u2,l0,l2), odd cols (u1,u3,l1,l3).
#define OUTROW(A, B, u0, u1, u2, u3, l0, l1, l2, l3, dst)                 \
  {                                                                       \
    f4 o;                                                                 \
    o.x = u0*A##0 + u2*A##1 + l0*B##0 + l2*B##1;                          \
    o.y = u1*A##1 + u3*A##2 + l1*B##1 + l3*B##2;                          \
    o.z = u0*A##1 + u2*A##2 + l0*B##1 + l2*B##2;                          \
    o.w = u1*A##2 + u3*A##3 + l1*B##2 + l3*B##3;                          \
    *reinterpret_cast<f4*>(dst) = o;                                      \
  }

__global__ __launch_bounds__(256) void upfirdn2d_up2_kernel(
    const float* __restrict__ x, const float* __restrict__ kern,
    float* __restrict__ out) {
  constexpr int H = 128, W = 128, OW = 256;

  const int tid = threadIdx.x;
  const int t   = tid & 63;                               // out cols 4t..4t+3
  const int rp  = ((blockIdx.x & 15) << 2) | (tid >> 6);  // row-pair 0..63 (wave-uniform)
  const int img = blockIdx.x >> 4;                        // 0..1023
  const int r0  = rp << 1;                                // 0,2,..,126

  // Flipped 4x4 kernel: w[ky][kx] = kern[(3-ky)*4 + (3-kx)].
  const float w00 = kern[15], w01 = kern[14], w02 = kern[13], w03 = kern[12];
  const float w10 = kern[11], w11 = kern[10], w12 = kern[9],  w13 = kern[8];
  const float w20 = kern[7],  w21 = kern[6],  w22 = kern[5],  w23 = kern[4];
  const float w30 = kern[3],  w31 = kern[2],  w32 = kern[1],  w33 = kern[0];

  const float* xi = x + (size_t)img * H * W;
  int c0 = 2 * t - 1;                            // want cols c0..c0+3
  c0 = c0 < 0 ? 0 : (c0 > W - 4 ? W - 4 : c0);   // clamp into the row

  // Rows r0-1, r0, r0+1, r0+2 (r0 and r0+1 always in-bounds).
  f4 va = {0.f, 0.f, 0.f, 0.f}, vc = {0.f, 0.f, 0.f, 0.f};
  const f4 vm = *reinterpret_cast<const f4u*>(xi + r0 * W + c0);
  const f4 vb = *reinterpret_cast<const f4u*>(xi + (r0 + 1) * W + c0);
  if (r0 > 0)     va = *reinterpret_cast<const f4u*>(xi + (r0 - 1) * W + c0);
  if (r0 + 2 < H) vc = *reinterpret_cast<const f4u*>(xi + (r0 + 2) * W + c0);

  const bool L = (t == 0), R = (t == 63);
  REMAP(va, a);
  REMAP(vm, m);
  REMAP(vb, b);
  REMAP(vc, d);

  float* dst = out + (size_t)img * OW * OW + (size_t)(2 * r0) * OW + 4 * t;
  OUTROW(a, m, w00, w01, w02, w03, w20, w21, w22, w23, dst);          // row 2r0
  OUTROW(m, b, w10, w11, w12, w13, w30, w31, w32, w33, dst + OW);     // row 2r0+1
  OUTROW(m, b, w00, w01, w02, w03, w20, w21, w22, w23, dst + 2*OW);   // row 2r0+2
  OUTROW(b, d, w10, w11, w12, w13, w30, w31, w32, w33, dst + 3*OW);   // row 2r0+3
}

extern "C" void kernel_launch(void* const* d_in, const int* in_sizes, int n_in,
                              void* d_out, int out_size, void* d_ws, size_t ws_size,
                              hipStream_t stream) {
  const float* x    = (const float*)d_in[0];
  const float* kern = (const float*)d_in[1];
  float* out        = (float*)d_out;
  // 1024 images x 16 blocks; block = 4 waves, each wave = one input
  // row-pair -> four full dense 1KB output rows.
  upfirdn2d_up2_kernel<<<dim3(1024 * 16), dim3(256), 0, stream>>>(x, kern, out);
}

// Round 13
// 53.838 us; speedup vs baseline: 1.2068x; 1.2068x over previous
//
#include <hip/hip_runtime.h>

// upfirdn2d specialized: up=2, down=1, pad0=2, eff trailing pad 2,
// 4x4 kernel, input (1024, 128, 128) f32 -> output (1024, 256, 256) f32.
//
// Lessons: (R8/R9) every store must be wave-dense (64 lanes x 16B = one
// contiguous 1KB output row). (R12) NT stores are +18% vs plain (write-
// allocate pollutes L2/L3). (R10/R11) sharing input rows across output
// rows amortizes loads: 12->10->8 VMEM/64B gave 60.4->57.1->55.2us.
// R13: row-QUAD per thread -- 6 loads + 8 dense NT stores per 128B
// output (7 VMEM/64B). Named scalars only.
//
// Polyphase (flipped kernel rows): out 2r   = w0x*in[r-1] + w2x*in[r]
//                                  out 2r+1 = w1x*in[r]   + w3x*in[r+1]
// Out cols 4t..4t+3 need in cols 2t-1..2t+2: one 4B-aligned f4 load per
// row, clamped at row ends, remapped with cndmasks.

typedef float f4 __attribute__((ext_vector_type(4)));
typedef f4 __attribute__((aligned(4))) f4u;  // 4B-aligned vector load

// Remap clamped load v to A0..A3 = in[2t-1 .. 2t+2] (zero-pad at edges).
#define REMAP(v, A)                                                       \
  const float A##0 = L ? 0.f : (R ? v.y : v.x);                           \
  const float A##1 = L ? v.x : (R ? v.z : v.y);                           \
  const float A##2 = L ? v.y : (R ? v.w : v.z);                           \
  const float A##3 = L ? v.z : (R ? 0.f : v.w);

// One output row (cols 4t..4t+3) from remapped rows A (upper) and B
// (lower): even cols use (u0,u2,l0,l2), odd cols (u1,u3,l1,l3).
#define OUTROW(A, B, u0, u1, u2, u3, l0, l1, l2, l3, dst)                 \
  {                                                                       \
    f4 o;                                                                 \
    o.x = u0*A##0 + u2*A##1 + l0*B##0 + l2*B##1;                          \
    o.y = u1*A##1 + u3*A##2 + l1*B##1 + l3*B##2;                          \
    o.z = u0*A##1 + u2*A##2 + l0*B##1 + l2*B##2;                          \
    o.w = u1*A##2 + u3*A##3 + l1*B##2 + l3*B##3;                          \
    __builtin_nontemporal_store(o, reinterpret_cast<f4*>(dst));           \
  }

__global__ __launch_bounds__(256) void upfirdn2d_up2_kernel(
    const float* __restrict__ x, const float* __restrict__ kern,
    float* __restrict__ out) {
  constexpr int H = 128, W = 128, OW = 256;

  const int tid = threadIdx.x;
  const int t   = tid & 63;                              // out cols 4t..4t+3
  const int rq  = ((blockIdx.x & 7) << 2) | (tid >> 6);  // row-quad 0..31 (wave-uniform)
  const int img = blockIdx.x >> 3;                       // 0..1023
  const int r0  = rq << 2;                               // 0,4,..,124

  // Flipped 4x4 kernel: w[ky][kx] = kern[(3-ky)*4 + (3-kx)].
  const float w00 = kern[15], w01 = kern[14], w02 = kern[13], w03 = kern[12];
  const float w10 = kern[11], w11 = kern[10], w12 = kern[9],  w13 = kern[8];
  const float w20 = kern[7],  w21 = kern[6],  w22 = kern[5],  w23 = kern[4];
  const float w30 = kern[3],  w31 = kern[2],  w32 = kern[1],  w33 = kern[0];

  const float* xi = x + (size_t)img * H * W;
  int c0 = 2 * t - 1;                            // want cols c0..c0+3
  c0 = c0 < 0 ? 0 : (c0 > W - 4 ? W - 4 : c0);   // clamp into the row

  // Rows r0-1 .. r0+4 (r0..r0+3 always in-bounds; ends guarded).
  f4 va = {0.f, 0.f, 0.f, 0.f}, vd = {0.f, 0.f, 0.f, 0.f};
  const f4 v0 = *reinterpret_cast<const f4u*>(xi + (r0    ) * W + c0);
  const f4 v1 = *reinterpret_cast<const f4u*>(xi + (r0 + 1) * W + c0);
  const f4 v2 = *reinterpret_cast<const f4u*>(xi + (r0 + 2) * W + c0);
  const f4 v3 = *reinterpret_cast<const f4u*>(xi + (r0 + 3) * W + c0);
  if (r0 > 0)     va = *reinterpret_cast<const f4u*>(xi + (r0 - 1) * W + c0);
  if (r0 + 4 < H) vd = *reinterpret_cast<const f4u*>(xi + (r0 + 4) * W + c0);

  const bool L = (t == 0), R = (t == 63);
  REMAP(va, a);
  REMAP(v0, p);
  REMAP(v1, q);
  REMAP(v2, s);
  REMAP(v3, u);
  REMAP(vd, d);

  float* dst = out + (size_t)img * OW * OW + (size_t)(2 * r0) * OW + 4 * t;
  OUTROW(a, p, w00, w01, w02, w03, w20, w21, w22, w23, dst);          // 2r0
  OUTROW(p, q, w10, w11, w12, w13, w30, w31, w32, w33, dst + OW);     // 2r0+1
  OUTROW(p, q, w00, w01, w02, w03, w20, w21, w22, w23, dst + 2*OW);   // 2r0+2
  OUTROW(q, s, w10, w11, w12, w13, w30, w31, w32, w33, dst + 3*OW);   // 2r0+3
  OUTROW(q, s, w00, w01, w02, w03, w20, w21, w22, w23, dst + 4*OW);   // 2r0+4
  OUTROW(s, u, w10, w11, w12, w13, w30, w31, w32, w33, dst + 5*OW);   // 2r0+5
  OUTROW(s, u, w00, w01, w02, w03, w20, w21, w22, w23, dst + 6*OW);   // 2r0+6
  OUTROW(u, d, w10, w11, w12, w13, w30, w31, w32, w33, dst + 7*OW);   // 2r0+7
}

extern "C" void kernel_launch(void* const* d_in, const int* in_sizes, int n_in,
                              void* d_out, int out_size, void* d_ws, size_t ws_size,
                              hipStream_t stream) {
  const float* x    = (const float*)d_in[0];
  const float* kern = (const float*)d_in[1];
  float* out        = (float*)d_out;
  // 1024 images x 8 blocks; block = 4 waves, each wave = one input
  // row-quad -> eight full dense 1KB output rows.
  upfirdn2d_up2_kernel<<<dim3(1024 * 8), dim3(256), 0, stream>>>(x, kern, out);
}

// Round 14
// 53.291 us; speedup vs baseline: 1.2192x; 1.0103x over previous
//
#include <hip/hip_runtime.h>

// upfirdn2d specialized: up=2, down=1, pad0=2, eff trailing pad 2,
// 4x4 kernel, input (1024, 128, 128) f32 -> output (1024, 256, 256) f32.
//
// Lessons: (R8/R9) every store must be wave-dense (64 lanes x 16B = one
// contiguous 1KB output row). (R12) NT stores +18% vs plain. (R10-R13)
// VMEM density ladder: 12->10->8->7 VMEM/64B = 60.4->57.1->55.2->53.8us.
// R14: row-OCTET per thread -- 10 loads + 16 dense NT stores per 256B
// output (6.5 VMEM/64B). Named scalars only.
//
// Polyphase (flipped kernel rows): out 2m   = w0x*in[m-1] + w2x*in[m]
//                                  out 2m+1 = w1x*in[m]   + w3x*in[m+1]
// Out cols 4t..4t+3 need in cols 2t-1..2t+2: one 4B-aligned f4 load per
// row, clamped at row ends, remapped with cndmasks.

typedef float f4 __attribute__((ext_vector_type(4)));
typedef f4 __attribute__((aligned(4))) f4u;  // 4B-aligned vector load

// Remap clamped load v to A0..A3 = in[2t-1 .. 2t+2] (zero-pad at edges).
#define REMAP(v, A)                                                       \
  const float A##0 = L ? 0.f : (R ? v.y : v.x);                           \
  const float A##1 = L ? v.x : (R ? v.z : v.y);                           \
  const float A##2 = L ? v.y : (R ? v.w : v.z);                           \
  const float A##3 = L ? v.z : (R ? 0.f : v.w);

// One output row (cols 4t..4t+3) from remapped rows A (upper) and B
// (lower): even cols use (u0,u2,l0,l2), odd cols (u1,u3,l1,l3).
#define OUTROW(A, B, u0, u1, u2, u3, l0, l1, l2, l3, dst)                 \
  {                                                                       \
    f4 o;                                                                 \
    o.x = u0*A##0 + u2*A##1 + l0*B##0 + l2*B##1;                          \
    o.y = u1*A##1 + u3*A##2 + l1*B##1 + l3*B##2;                          \
    o.z = u0*A##1 + u2*A##2 + l0*B##1 + l2*B##2;                          \
    o.w = u1*A##2 + u3*A##3 + l1*B##2 + l3*B##3;                          \
    __builtin_nontemporal_store(o, reinterpret_cast<f4*>(dst));           \
  }

__global__ __launch_bounds__(256) void upfirdn2d_up2_kernel(
    const float* __restrict__ x, const float* __restrict__ kern,
    float* __restrict__ out) {
  constexpr int H = 128, W = 128, OW = 256;

  const int tid = threadIdx.x;
  const int t   = tid & 63;                              // out cols 4t..4t+3
  const int ro  = ((blockIdx.x & 3) << 2) | (tid >> 6);  // row-octet 0..15 (wave-uniform)
  const int img = blockIdx.x >> 2;                       // 0..1023
  const int r0  = ro << 3;                               // 0,8,..,120

  // Flipped 4x4 kernel: w[ky][kx] = kern[(3-ky)*4 + (3-kx)].
  const float w00 = kern[15], w01 = kern[14], w02 = kern[13], w03 = kern[12];
  const float w10 = kern[11], w11 = kern[10], w12 = kern[9],  w13 = kern[8];
  const float w20 = kern[7],  w21 = kern[6],  w22 = kern[5],  w23 = kern[4];
  const float w30 = kern[3],  w31 = kern[2],  w32 = kern[1],  w33 = kern[0];

  const float* xi = x + (size_t)img * H * W;
  int c0 = 2 * t - 1;                            // want cols c0..c0+3
  c0 = c0 < 0 ? 0 : (c0 > W - 4 ? W - 4 : c0);   // clamp into the row

  // Rows r0-1 .. r0+8 (r0..r0+7 always in-bounds; ends guarded).
  f4 va = {0.f, 0.f, 0.f, 0.f}, vj = {0.f, 0.f, 0.f, 0.f};
  const f4 v0 = *reinterpret_cast<const f4u*>(xi + (r0    ) * W + c0);
  const f4 v1 = *reinterpret_cast<const f4u*>(xi + (r0 + 1) * W + c0);
  const f4 v2 = *reinterpret_cast<const f4u*>(xi + (r0 + 2) * W + c0);
  const f4 v3 = *reinterpret_cast<const f4u*>(xi + (r0 + 3) * W + c0);
  const f4 v4 = *reinterpret_cast<const f4u*>(xi + (r0 + 4) * W + c0);
  const f4 v5 = *reinterpret_cast<const f4u*>(xi + (r0 + 5) * W + c0);
  const f4 v6 = *reinterpret_cast<const f4u*>(xi + (r0 + 6) * W + c0);
  const f4 v7 = *reinterpret_cast<const f4u*>(xi + (r0 + 7) * W + c0);
  if (r0 > 0)     va = *reinterpret_cast<const f4u*>(xi + (r0 - 1) * W + c0);
  if (r0 + 8 < H) vj = *reinterpret_cast<const f4u*>(xi + (r0 + 8) * W + c0);

  const bool L = (t == 0), R = (t == 63);
  REMAP(va, ra);
  REMAP(v0, rb);
  REMAP(v1, rc);
  REMAP(v2, rd);
  REMAP(v3, re);
  REMAP(v4, rf);
  REMAP(v5, rg);
  REMAP(v6, rh);
  REMAP(v7, ri);
  REMAP(vj, rj);

  float* dst = out + (size_t)img * OW * OW + (size_t)(2 * r0) * OW + 4 * t;
  OUTROW(ra, rb, w00, w01, w02, w03, w20, w21, w22, w23, dst);
  OUTROW(rb, rc, w10, w11, w12, w13, w30, w31, w32, w33, dst + OW);
  OUTROW(rb, rc, w00, w01, w02, w03, w20, w21, w22, w23, dst + 2*OW);
  OUTROW(rc, rd, w10, w11, w12, w13, w30, w31, w32, w33, dst + 3*OW);
  OUTROW(rc, rd, w00, w01, w02, w03, w20, w21, w22, w23, dst + 4*OW);
  OUTROW(rd, re, w10, w11, w12, w13, w30, w31, w32, w33, dst + 5*OW);
  OUTROW(rd, re, w00, w01, w02, w03, w20, w21, w22, w23, dst + 6*OW);
  OUTROW(re, rf, w10, w11, w12, w13, w30, w31, w32, w33, dst + 7*OW);
  OUTROW(re, rf, w00, w01, w02, w03, w20, w21, w22, w23, dst + 8*OW);
  OUTROW(rf, rg, w10, w11, w12, w13, w30, w31, w32, w33, dst + 9*OW);
  OUTROW(rf, rg, w00, w01, w02, w03, w20, w21, w22, w23, dst + 10*OW);
  OUTROW(rg, rh, w10, w11, w12, w13, w30, w31, w32, w33, dst + 11*OW);
  OUTROW(rg, rh, w00, w01, w02, w03, w20, w21, w22, w23, dst + 12*OW);
  OUTROW(rh, ri, w10, w11, w12, w13, w30, w31, w32, w33, dst + 13*OW);
  OUTROW(rh, ri, w00, w01, w02, w03, w20, w21, w22, w23, dst + 14*OW);
  OUTROW(ri, rj, w10, w11, w12, w13, w30, w31, w32, w33, dst + 15*OW);
}

extern "C" void kernel_launch(void* const* d_in, const int* in_sizes, int n_in,
                              void* d_out, int out_size, void* d_ws, size_t ws_size,
                              hipStream_t stream) {
  const float* x    = (const float*)d_in[0];
  const float* kern = (const float*)d_in[1];
  float* out        = (float*)d_out;
  // 1024 images x 4 blocks; block = 4 waves, each wave = one input
  // row-octet -> sixteen full dense 1KB output rows.
  upfirdn2d_up2_kernel<<<dim3(1024 * 4), dim3(256), 0, stream>>>(x, kern, out);
}